// Round 12
// baseline (83886.774 us; speedup 1.0000x reference)
//
#include <hip/hip_runtime.h>

#define T_STEPS 1000
#define BATCH   256
#define IN_DIM  128
#define HID     512
#define OUT_DIM 32
#define ALPHA_F 0.2f
#define OMA_F   0.8f
#define MAXNNZ  96   // Binomial(511,0.1) max over 512 rows ~ 75; 96 is 6.5 sigma
#define BDEPTH  20   // per-(lane,bank) bucket depth; P(overflow) ~ 0
#define NWORK   256
#define IN_TILES  8000   // 1000 mb x 8 nc(64 cols)
#define OUT_TILES 500    // 512-row tiles

// ---- workspace layout (byte offsets, all 16B aligned) ----
// val_t : float  [HID][MAXNNZ]                          @ 0        (196608 B)
// idx_t : ushort [HID][MAXNNZ]                          @ 196608   (98304 B)
// perm  : uint   [HID]                                  @ 294912   (2048 B)
// nnzR  : uint   [HID]  nnz -> sched S                  @ 296960   (2048 B)
// w_inT : float  [IN_DIM][HID]                          @ 299008   (262144 B)
// fcT   : float  [HID][OUT_DIM]                         @ 561152   (65536 B)
// inflag: uint   [1000] ingemm tile completion (==8)    @ 626688   (4096 B)
// prog  : int    [256]  scan progress per batch row     @ 630784   (1024 B)

// ============================================================
// K2a: counts + deterministic rank (stable sort by (c, h)).
// ============================================================
__global__ __launch_bounds__(512) void build_rank_kernel(
    const float* __restrict__ w_h, const float* __restrict__ sparse,
    unsigned int* __restrict__ perm, unsigned int* __restrict__ nnzR)
{
    int tid = threadIdx.x;           // row h
    __shared__ int cnt_sh[HID];

    const float4* wr4 = (const float4*)(w_h    + tid * HID);
    const float4* sr4 = (const float4*)(sparse + tid * HID);
    int cnt = 0;
    for (int j4 = 0; j4 < HID / 4; j4++) {
        float4 w = wr4[j4];
        float4 s = sr4[j4];
        if (w.x > 0.f && s.x > 0.5f) cnt++;
        if (w.y > 0.f && s.y > 0.5f) cnt++;
        if (w.z > 0.f && s.z > 0.5f) cnt++;
        if (w.w > 0.f && s.w > 0.5f) cnt++;
    }
    int c = min(cnt, MAXNNZ);

    cnt_sh[tid] = c;
    __syncthreads();
    int rank = 0;
    for (int j = 0; j < HID; j++) {
        int cj = cnt_sh[j];                     // broadcast read
        rank += (cj < c) || (cj == c && j < tid);
    }
    perm[rank] = (unsigned int)tid;
    nnzR[rank] = (unsigned int)c;
}

// ============================================================
// K2b: wave-parallel fill, one rank per block (1 wave).
// ============================================================
__global__ __launch_bounds__(64) void fill_kernel(
    const float* __restrict__ w_h, const float* __restrict__ dale,
    const float* __restrict__ sparse,
    const unsigned int* __restrict__ perm, const unsigned int* __restrict__ nnzR,
    float* __restrict__ val_t, unsigned short* __restrict__ idx_t)
{
    int r    = blockIdx.x;           // rank
    int lane = threadIdx.x;          // 0..63
    int h = (int)perm[r];
    int c = (int)nnzR[r];

    float*          vout = val_t + r * MAXNNZ;
    unsigned short* iout = idx_t + r * MAXNNZ;

    for (int k = lane; k < MAXNNZ; k += 64)
        if (k >= c) { vout[k] = 0.f; iout[k] = 0; }

    unsigned long long lt = (1ull << lane) - 1ull;
    int pos_base = 0;
#pragma unroll
    for (int ch = 0; ch < 8; ch++) {
        int j = ch * 64 + lane;
        float w = w_h[h * HID + j];
        float s = sparse[h * HID + j];
        bool pred = (w > 0.f) && (s > 0.5f);
        unsigned long long m = __ballot(pred);
        if (pred) {
            int pos = pos_base + (int)__popcll(m & lt);
            if (pos < MAXNNZ) {
                vout[pos] = w * dale[j];
                iout[pos] = (unsigned short)(j * 4);   // LDS byte offset
            }
        }
        pos_base += (int)__popcll(m);
    }
}

// ============================================================
// K2d: capped gather scheduler (R11 — proven deterministic).
// ============================================================
__global__ __launch_bounds__(64) void sched_kernel(
    float* __restrict__ val_t, unsigned short* __restrict__ idx_t,
    unsigned int* __restrict__ nnzR)
{
    int w    = blockIdx.x;           // scan-wave id 0..7
    int lane = threadIdx.x;          // 0..63
    int rank = w * 64 + lane;
    int g    = lane >> 5;            // phase-group 0/1
    int l32  = lane & 31;

    __shared__ unsigned short entb[64][32][BDEPTH]; // (src<<9)|word
    __shared__ unsigned char  cntb[64][32];
    __shared__ unsigned char  outsrc[64][MAXNNZ];
    __shared__ float          vll[64][MAXNNZ];
    __shared__ volatile int   wbuf[2][32];

    int c = (int)nnzR[rank];
    int S = c;
#pragma unroll
    for (int off = 32; off; off >>= 1) S = max(S, __shfl_xor(S, off));

    for (int b = 0; b < 32; b++) cntb[lane][b] = 0;
    for (int e = 0; e < MAXNNZ; e++) {
        vll[lane][e]    = val_t[rank * MAXNNZ + e];
        outsrc[lane][e] = 255;
    }
    unsigned int bm = 0;
    int rem = 0;
    for (int e = 0; e < c; e++) {
        int word = ((int)idx_t[rank * MAXNNZ + e]) >> 2;  // 0..511
        int b = word & 31;
        int k = (int)cntb[lane][b];
        if (k < BDEPTH) {
            entb[lane][b][k] = (unsigned short)((e << 9) | word);
            cntb[lane][b] = (unsigned char)(k + 1);
            bm |= 1u << b;
            rem++;
        }
    }

    for (int s = 0; s < MAXNNZ; s++) {
        if (s < S) {
            unsigned int claimed = 0;
            int myb = -1;
#pragma unroll
            for (int round = 0; round < 2; round++) {
                int prop = -1;
                if (myb < 0 && rem > 0) {
                    unsigned int avail = bm & ~claimed;
                    if (avail) {
                        int rot = (l32 * 7 + s * 3 + round * 11) & 31;
                        unsigned int av2 = (avail >> rot) | (avail << ((32 - rot) & 31));
                        prop = (__ffs(av2) - 1 + rot) & 31;
                    }
                }
                if (prop >= 0) wbuf[g][prop] = lane;        // race: HW lane priority
                int won = 0;
                if (prop >= 0 && wbuf[g][prop] == lane) { myb = prop; won = 1; }
                unsigned int cm = won ? (1u << myb) : 0u;
#pragma unroll
                for (int off = 16; off; off >>= 1)
                    cm |= (unsigned int)__shfl_xor((int)cm, off, 32);
                claimed |= cm;
            }
            if (myb < 0 && rem > 0 && rem >= S - s) {       // forced (rare)
                unsigned int a = bm & ~claimed;
                myb = a ? (__ffs(a) - 1) : (__ffs(bm) - 1);
            }
            if (myb >= 0) {
                int k = (int)cntb[lane][myb] - 1;
                unsigned short pk = entb[lane][myb][k];
                cntb[lane][myb] = (unsigned char)k;
                if (k == 0) bm &= ~(1u << myb);
                outsrc[lane][s] = (unsigned char)(pk >> 9);
                idx_t[rank * MAXNNZ + s] = (unsigned short)((pk & 511) * 4);
                rem--;
            } else {
                unsigned int freeb = ~claimed;
                int pb = freeb ? (__ffs(freeb) - 1) : 0;
                idx_t[rank * MAXNNZ + s] = (unsigned short)(pb * 4);
            }
        } else {
            idx_t[rank * MAXNNZ + s] = 0;
        }
    }
    nnzR[rank] = (unsigned int)S;

    for (int s = 0; s < MAXNNZ; s++) {
        int src = outsrc[lane][s];
        val_t[rank * MAXNNZ + s] = (src == 255) ? 0.f : vll[lane][src];
    }
}

// ============================================================
// K2c: weight transposes + flag init, grid-parallel.
// ============================================================
__global__ __launch_bounds__(256) void trans_kernel(
    const float* __restrict__ w_in, const float* __restrict__ fc_w,
    float* __restrict__ w_inT, float* __restrict__ fcT,
    unsigned int* __restrict__ inflag, int* __restrict__ prog)
{
    int o = blockIdx.x * 256 + threadIdx.x;
    if (o < IN_DIM * HID) {
        int k = o / HID, n = o % HID;          // w_inT[k][n] = w_in[n][k]
        w_inT[o] = w_in[n * IN_DIM + k];
    } else {
        int o2 = o - IN_DIM * HID;
        if (o2 < HID * OUT_DIM) {
            int k = o2 / OUT_DIM, oo = o2 % OUT_DIM;   // fcT[k][o] = fc_w[o][k]
            fcT[o2] = fc_w[oo * HID + k];
        }
    }
    if (o < T_STEPS) inflag[o] = 0u;           // re-init every launch
    if (o < BATCH)   prog[o]   = -1;
}

// ============================================================
// K3-fused: persistent pipelined kernel, 512 blocks (2/CU exact).
//  blocks [0,256): scan rows (R11 numerics, unchanged order).
//  blocks [256,512): workers — phase 1 ingemm tiles (produce
//  inflag[t] via release atomics), phase 2 outgemm tiles (gated
//  on scan prog[b], release-signaled every 8 steps).
//  Cross-XCD visibility: release = barrier-drain + __threadfence
//  (agent) + agent atomic; acquire = agent atomic load.
//  Sync gates timing only — values are write-once — so outputs
//  remain bit-identical to the unfused R11 pipeline.
// ============================================================

#define PAIR2(base, ii)                                              \
    {                                                                \
        unsigned int pk = idp[ii];                                   \
        float g0 = *(const float*)((base) + (pk & 0xffffu));         \
        float g1 = *(const float*)((base) + (pk >> 16));             \
        a0 = fmaf(val[2*(ii)],     g0, a0);                          \
        a1 = fmaf(val[2*(ii) + 1], g1, a1);                          \
    }

#define CHUNK2(base, c)                                              \
    PAIR2(base, 2*(c)+0) PAIR2(base, 2*(c)+1)

__device__ __forceinline__ float sparse_accum(
    const char* base, const float (&val)[MAXNNZ],
    const unsigned int (&idp)[MAXNNZ / 2], int nch, float a_init)
{
    float a0 = a_init, a1 = 0.f;
    switch (nch) {
        case 24: CHUNK2(base, 23) [[fallthrough]];
        case 23: CHUNK2(base, 22) [[fallthrough]];
        case 22: CHUNK2(base, 21) [[fallthrough]];
        case 21: CHUNK2(base, 20) [[fallthrough]];
        case 20: CHUNK2(base, 19) [[fallthrough]];
        case 19: CHUNK2(base, 18) [[fallthrough]];
        case 18: CHUNK2(base, 17) [[fallthrough]];
        case 17: CHUNK2(base, 16) [[fallthrough]];
        case 16: CHUNK2(base, 15) [[fallthrough]];
        case 15: CHUNK2(base, 14) [[fallthrough]];
        case 14: CHUNK2(base, 13) [[fallthrough]];
        case 13: CHUNK2(base, 12) [[fallthrough]];
        case 12: CHUNK2(base, 11) [[fallthrough]];
        case 11: CHUNK2(base, 10) [[fallthrough]];
        case 10: CHUNK2(base,  9) [[fallthrough]];
        case  9: CHUNK2(base,  8) [[fallthrough]];
        case  8: CHUNK2(base,  7) [[fallthrough]];
        case  7: CHUNK2(base,  6) [[fallthrough]];
        case  6: CHUNK2(base,  5) [[fallthrough]];
        case  5: CHUNK2(base,  4) [[fallthrough]];
        case  4: CHUNK2(base,  3) [[fallthrough]];
        case  3: CHUNK2(base,  2) [[fallthrough]];
        case  2: CHUNK2(base,  1) [[fallthrough]];
        case  1: CHUNK2(base,  0) break;
        default: break;
    }
    return a0 + a1;
}

__device__ __forceinline__ void wait_inflag(unsigned int* f)
{
    while (__hip_atomic_load(f, __ATOMIC_ACQUIRE, __HIP_MEMORY_SCOPE_AGENT) != 8u)
        __builtin_amdgcn_s_sleep(8);
}

__global__ __launch_bounds__(512, 4) void fused_kernel(
    const float* __restrict__ x, const float* __restrict__ w_inT,
    const float* __restrict__ b_in, const float* __restrict__ b_h,
    float* __restrict__ act_g,
    const float* __restrict__ val_t, const unsigned short* __restrict__ idx_t,
    const unsigned int* __restrict__ perm, const unsigned int* __restrict__ nnzR,
    const float* __restrict__ fcT, const float* __restrict__ fc_b,
    float* __restrict__ out_g,
    unsigned int* __restrict__ inflag, int* __restrict__ prog)
{
    __shared__ float smem[8704];     // scan: 1024 | ingemm: 256*33 | outgemm: 512*17
    int bid = blockIdx.x;
    int tid = threadIdx.x;

    if (bid < BATCH) {
        // ----------------- SCAN role -----------------
        int b = bid;
        float* sbuf = smem;
        sbuf[tid] = 0.f;

        float        val[MAXNNZ];
        unsigned int idp[MAXNNZ / 2];
        {
            const float4* vp = (const float4*)(val_t + tid * MAXNNZ);
#pragma unroll
            for (int i = 0; i < MAXNNZ / 4; i++) {
                float4 v = vp[i];
                val[4*i] = v.x; val[4*i+1] = v.y; val[4*i+2] = v.z; val[4*i+3] = v.w;
            }
            const uint4* ip = (const uint4*)(idx_t + tid * MAXNNZ);
#pragma unroll
            for (int i = 0; i < MAXNNZ / 8; i++) {
                uint4 u = ip[i];
                idp[4*i] = u.x; idp[4*i+1] = u.y; idp[4*i+2] = u.z; idp[4*i+3] = u.w;
            }
        }
        int h = (int)perm[tid];
        int wmax = (int)nnzR[tid | 63];
        wmax = __builtin_amdgcn_readfirstlane(wmax);
        int nch = (wmax + 3) >> 2;

        float state = 0.f;
        int gi = b * HID + h;
        wait_inflag(&inflag[0]);
        float xdv = act_g[gi];                          // xd[0]
        const char* sb = (const char*)sbuf;
        __syncthreads();

        for (int t = 0; t < T_STEPS; t += 2) {
            { // step t (even)
                wait_inflag(&inflag[t + 1]);
                float xn = act_g[gi + BATCH * HID];     // xd[t+1]
                float a = sparse_accum(sb, val, idp, nch, xdv);
                state = state * OMA_F + a * ALPHA_F;
                float act = fmaxf(state, 0.f);
                sbuf[512 + h] = act;
                __syncthreads();                        // drains stores of step t-1
                act_g[gi] = act;
                if (t && (t & 7) == 0 && tid == 0) {    // steps <= t-1 visible
                    __threadfence();
                    __hip_atomic_store(&prog[b], t - 1, __ATOMIC_RELEASE,
                                       __HIP_MEMORY_SCOPE_AGENT);
                }
                gi += BATCH * HID;
                xdv = xn;
            }
            { // step t+1 (odd)
                bool more = (t < T_STEPS - 2);
                if (more) wait_inflag(&inflag[t + 2]);
                int gn = more ? gi + BATCH * HID : gi;
                float xn = act_g[gn];
                float a = sparse_accum(sb + 2048, val, idp, nch, xdv);
                state = state * OMA_F + a * ALPHA_F;
                float act = fmaxf(state, 0.f);
                sbuf[h] = act;
                __syncthreads();
                act_g[gi] = act;
                gi += BATCH * HID;
                xdv = xn;
            }
        }
        __syncthreads();                                // drain final stores
        if (tid == 0) {
            __threadfence();
            __hip_atomic_store(&prog[b], T_STEPS - 1, __ATOMIC_RELEASE,
                               __HIP_MEMORY_SCOPE_AGENT);
        }
    } else {
        // ----------------- WORKER role -----------------
        int w = bid - BATCH;

        // phase 1: ingemm tiles (256 rows x 64 cols, 512 threads)
        {
            int r = tid & 255, half = tid >> 8;
            for (int tile = w; tile < IN_TILES; tile += NWORK) {
                int mb = tile >> 3;
                long m0 = (long)mb * 256;
                int n0 = (tile & 7) * 64 + half * 32;
                float acc[32];
#pragma unroll
                for (int j = 0; j < 32; j++) acc[j] = b_in[n0 + j] + b_h[n0 + j];
                for (int k0 = 0; k0 < IN_DIM; k0 += 32) {
                    __syncthreads();
#pragma unroll
                    for (int i = 0; i < 4; i++) {
                        int f = tid + i * 512, rr = f >> 3, cc = f & 7;
                        float4 v = *(const float4*)(x + (m0 + rr) * IN_DIM + k0 + cc * 4);
                        float* d = &smem[rr * 33 + cc * 4];
                        d[0] = v.x; d[1] = v.y; d[2] = v.z; d[3] = v.w;
                    }
                    __syncthreads();
                    const float* xrow = &smem[r * 33];
#pragma unroll
                    for (int kk = 0; kk < 32; kk++) {
                        float a = xrow[kk];
                        const float* wrow = w_inT + (k0 + kk) * HID + n0;
#pragma unroll
                        for (int j = 0; j < 32; j++) acc[j] = fmaf(a, wrow[j], acc[j]);
                    }
                }
                float* orow = act_g + (m0 + r) * HID + n0;
#pragma unroll
                for (int j = 0; j < 8; j++)
                    *(float4*)(orow + j * 4) =
                        make_float4(acc[4*j], acc[4*j+1], acc[4*j+2], acc[4*j+3]);
                __syncthreads();                        // all waves' stores drained
                if (tid == 0) {
                    __threadfence();
                    __hip_atomic_fetch_add(&inflag[mb], 1u, __ATOMIC_RELEASE,
                                           __HIP_MEMORY_SCOPE_AGENT);
                }
            }
        }

        // phase 2: outgemm tiles (512 rows = 2 timesteps, k-tile 16)
        {
            int bb = tid & 255, th = tid >> 8;
            for (int tile = w; tile < OUT_TILES; tile += NWORK) {
                long m0 = (long)tile * 512;
                int need = 2 * tile + th;
                while (__hip_atomic_load(&prog[bb], __ATOMIC_ACQUIRE,
                                         __HIP_MEMORY_SCOPE_AGENT) < need)
                    __builtin_amdgcn_s_sleep(32);
                __syncthreads();                        // all flags confirmed
                float acc[32];
#pragma unroll
                for (int o = 0; o < 32; o++) acc[o] = fc_b[o];
                for (int k0 = 0; k0 < HID; k0 += 16) {
                    __syncthreads();
#pragma unroll
                    for (int i = 0; i < 4; i++) {
                        int f = tid + i * 512, rr = f >> 2, cc = f & 3;
                        float4 v = *(const float4*)(act_g + (m0 + rr) * HID + k0 + cc * 4);
                        float* d = &smem[rr * 17 + cc * 4];
                        d[0] = v.x; d[1] = v.y; d[2] = v.z; d[3] = v.w;
                    }
                    __syncthreads();
                    const float* arow = &smem[tid * 17];
#pragma unroll
                    for (int kk = 0; kk < 16; kk++) {
                        float a = arow[kk];
                        const float* frow = fcT + (k0 + kk) * OUT_DIM;
#pragma unroll
                        for (int o = 0; o < 32; o++) acc[o] = fmaf(a, frow[o], acc[o]);
                    }
                }
                float* orow = out_g + (m0 + tid) * OUT_DIM;
#pragma unroll
                for (int j = 0; j < 8; j++)
                    *(float4*)(orow + j * 4) =
                        make_float4(acc[4*j], acc[4*j+1], acc[4*j+2], acc[4*j+3]);
            }
        }
    }
}

// ============================================================
extern "C" void kernel_launch(void* const* d_in, const int* in_sizes, int n_in,
                              void* d_out, int out_size, void* d_ws, size_t ws_size,
                              hipStream_t stream)
{
    const float* x      = (const float*)d_in[0];
    const float* w_in   = (const float*)d_in[1];
    const float* b_in   = (const float*)d_in[2];
    const float* w_h    = (const float*)d_in[3];
    const float* b_h    = (const float*)d_in[4];
    const float* dale   = (const float*)d_in[5];
    const float* sparse = (const float*)d_in[6];
    const float* fc_w   = (const float*)d_in[7];
    const float* fc_b   = (const float*)d_in[8];

    float* out_g = (float*)d_out;
    float* act_g = out_g + (long)T_STEPS * BATCH * OUT_DIM;  // rnn_activity slab

    char* ws = (char*)d_ws;
    float*          val_t  = (float*)(ws + 0);
    unsigned short* idx_t  = (unsigned short*)(ws + 196608);
    unsigned int*   perm   = (unsigned int*)(ws + 294912);
    unsigned int*   nnzR   = (unsigned int*)(ws + 296960);
    float*          w_inT  = (float*)(ws + 299008);
    float*          fcT    = (float*)(ws + 561152);
    unsigned int*   inflag = (unsigned int*)(ws + 626688);
    int*            prog   = (int*)(ws + 630784);

    build_rank_kernel<<<1, 512, 0, stream>>>(w_h, sparse, perm, nnzR);
    fill_kernel<<<HID, 64, 0, stream>>>(w_h, dale, sparse, perm, nnzR, val_t, idx_t);
    sched_kernel<<<8, 64, 0, stream>>>(val_t, idx_t, nnzR);
    trans_kernel<<<320, 256, 0, stream>>>(w_in, fc_w, w_inT, fcT, inflag, prog);
    fused_kernel<<<512, 512, 0, stream>>>(x, w_inT, b_in, b_h, act_g,
                                          val_t, idx_t, perm, nnzR,
                                          fcT, fc_b, out_g, inflag, prog);
}

// Round 14
// 3910.873 us; speedup vs baseline: 21.4496x; 21.4496x over previous
//
#include <hip/hip_runtime.h>

#define T_STEPS 1000
#define BATCH   256
#define IN_DIM  128
#define HID     512
#define OUT_DIM 32
#define ALPHA_F 0.2f
#define OMA_F   0.8f
#define MAXNNZ  96   // Binomial(511,0.1) max over 512 rows ~ 75; 96 is 6.5 sigma
#define BDEPTH  20   // per-(lane,bank) bucket depth; P(overflow) ~ 0

// ---- workspace layout (byte offsets, all 16B aligned) ----
// val_t : float  [HID][MAXNNZ]                          @ 0        (196608 B)
// idx_t : ushort [HID][MAXNNZ]                          @ 196608   (98304 B)
// perm  : uint   [HID]                                  @ 294912   (2048 B)
// nnzR  : uint   [HID]  nnz -> sched S                  @ 296960   (2048 B)
// w_inT : float  [IN_DIM][HID]                          @ 299008   (262144 B)
// fcT   : float  [HID][OUT_DIM]                         @ 561152   (65536 B)

// ============================================================
// K2a: counts + deterministic rank (stable sort by (c, h)).
// ============================================================
__global__ __launch_bounds__(512) void build_rank_kernel(
    const float* __restrict__ w_h, const float* __restrict__ sparse,
    unsigned int* __restrict__ perm, unsigned int* __restrict__ nnzR)
{
    int tid = threadIdx.x;           // row h
    __shared__ int cnt_sh[HID];

    const float4* wr4 = (const float4*)(w_h    + tid * HID);
    const float4* sr4 = (const float4*)(sparse + tid * HID);
    int cnt = 0;
    for (int j4 = 0; j4 < HID / 4; j4++) {
        float4 w = wr4[j4];
        float4 s = sr4[j4];
        if (w.x > 0.f && s.x > 0.5f) cnt++;
        if (w.y > 0.f && s.y > 0.5f) cnt++;
        if (w.z > 0.f && s.z > 0.5f) cnt++;
        if (w.w > 0.f && s.w > 0.5f) cnt++;
    }
    int c = min(cnt, MAXNNZ);

    cnt_sh[tid] = c;
    __syncthreads();
    int rank = 0;
    for (int j = 0; j < HID; j++) {
        int cj = cnt_sh[j];                     // broadcast read
        rank += (cj < c) || (cj == c && j < tid);
    }
    perm[rank] = (unsigned int)tid;
    nnzR[rank] = (unsigned int)c;
}

// ============================================================
// K2b: wave-parallel fill, one rank per block (1 wave).
// ============================================================
__global__ __launch_bounds__(64) void fill_kernel(
    const float* __restrict__ w_h, const float* __restrict__ dale,
    const float* __restrict__ sparse,
    const unsigned int* __restrict__ perm, const unsigned int* __restrict__ nnzR,
    float* __restrict__ val_t, unsigned short* __restrict__ idx_t)
{
    int r    = blockIdx.x;           // rank
    int lane = threadIdx.x;          // 0..63
    int h = (int)perm[r];
    int c = (int)nnzR[r];

    float*          vout = val_t + r * MAXNNZ;
    unsigned short* iout = idx_t + r * MAXNNZ;

    for (int k = lane; k < MAXNNZ; k += 64)
        if (k >= c) { vout[k] = 0.f; iout[k] = 0; }

    unsigned long long lt = (1ull << lane) - 1ull;
    int pos_base = 0;
#pragma unroll
    for (int ch = 0; ch < 8; ch++) {
        int j = ch * 64 + lane;
        float w = w_h[h * HID + j];
        float s = sparse[h * HID + j];
        bool pred = (w > 0.f) && (s > 0.5f);
        unsigned long long m = __ballot(pred);
        if (pred) {
            int pos = pos_base + (int)__popcll(m & lt);
            if (pos < MAXNNZ) {
                vout[pos] = w * dale[j];
                iout[pos] = (unsigned short)(j * 4);   // LDS byte offset
            }
        }
        pos_base += (int)__popcll(m);
    }
}

// ============================================================
// K2d: capped gather scheduler (R11 — proven deterministic,
//      conflicts 3.43e8 -> 2.05e8, scan 1418 -> 1275us).
// ============================================================
__global__ __launch_bounds__(64) void sched_kernel(
    float* __restrict__ val_t, unsigned short* __restrict__ idx_t,
    unsigned int* __restrict__ nnzR)
{
    int w    = blockIdx.x;           // scan-wave id 0..7
    int lane = threadIdx.x;          // 0..63
    int rank = w * 64 + lane;
    int g    = lane >> 5;            // phase-group 0/1
    int l32  = lane & 31;

    __shared__ unsigned short entb[64][32][BDEPTH]; // (src<<9)|word
    __shared__ unsigned char  cntb[64][32];
    __shared__ unsigned char  outsrc[64][MAXNNZ];
    __shared__ float          vll[64][MAXNNZ];
    __shared__ volatile int   wbuf[2][32];

    int c = (int)nnzR[rank];
    int S = c;
#pragma unroll
    for (int off = 32; off; off >>= 1) S = max(S, __shfl_xor(S, off));

    for (int b = 0; b < 32; b++) cntb[lane][b] = 0;
    for (int e = 0; e < MAXNNZ; e++) {
        vll[lane][e]    = val_t[rank * MAXNNZ + e];
        outsrc[lane][e] = 255;
    }
    unsigned int bm = 0;
    int rem = 0;
    for (int e = 0; e < c; e++) {
        int word = ((int)idx_t[rank * MAXNNZ + e]) >> 2;  // 0..511
        int b = word & 31;
        int k = (int)cntb[lane][b];
        if (k < BDEPTH) {
            entb[lane][b][k] = (unsigned short)((e << 9) | word);
            cntb[lane][b] = (unsigned char)(k + 1);
            bm |= 1u << b;
            rem++;
        }
    }

    for (int s = 0; s < MAXNNZ; s++) {
        if (s < S) {
            unsigned int claimed = 0;
            int myb = -1;
#pragma unroll
            for (int round = 0; round < 2; round++) {
                int prop = -1;
                if (myb < 0 && rem > 0) {
                    unsigned int avail = bm & ~claimed;
                    if (avail) {
                        int rot = (l32 * 7 + s * 3 + round * 11) & 31;
                        unsigned int av2 = (avail >> rot) | (avail << ((32 - rot) & 31));
                        prop = (__ffs(av2) - 1 + rot) & 31;
                    }
                }
                if (prop >= 0) wbuf[g][prop] = lane;        // race: HW lane priority
                int won = 0;
                if (prop >= 0 && wbuf[g][prop] == lane) { myb = prop; won = 1; }
                unsigned int cm = won ? (1u << myb) : 0u;
#pragma unroll
                for (int off = 16; off; off >>= 1)
                    cm |= (unsigned int)__shfl_xor((int)cm, off, 32);
                claimed |= cm;
            }
            if (myb < 0 && rem > 0 && rem >= S - s) {       // forced (rare)
                unsigned int a = bm & ~claimed;
                myb = a ? (__ffs(a) - 1) : (__ffs(bm) - 1);
            }
            if (myb >= 0) {
                int k = (int)cntb[lane][myb] - 1;
                unsigned short pk = entb[lane][myb][k];
                cntb[lane][myb] = (unsigned char)k;
                if (k == 0) bm &= ~(1u << myb);
                outsrc[lane][s] = (unsigned char)(pk >> 9);
                idx_t[rank * MAXNNZ + s] = (unsigned short)((pk & 511) * 4);
                rem--;
            } else {
                unsigned int freeb = ~claimed;
                int pb = freeb ? (__ffs(freeb) - 1) : 0;
                idx_t[rank * MAXNNZ + s] = (unsigned short)(pb * 4);
            }
        } else {
            idx_t[rank * MAXNNZ + s] = 0;
        }
    }
    nnzR[rank] = (unsigned int)S;

    for (int s = 0; s < MAXNNZ; s++) {
        int src = outsrc[lane][s];
        val_t[rank * MAXNNZ + s] = (src == 255) ? 0.f : vll[lane][src];
    }
}

// ============================================================
// K2c: weight transposes, grid-parallel.
// ============================================================
__global__ __launch_bounds__(256) void trans_kernel(
    const float* __restrict__ w_in, const float* __restrict__ fc_w,
    float* __restrict__ w_inT, float* __restrict__ fcT)
{
    int o = blockIdx.x * 256 + threadIdx.x;
    if (o < IN_DIM * HID) {
        int k = o / HID, n = o % HID;          // w_inT[k][n] = w_in[n][k]
        w_inT[o] = w_in[n * IN_DIM + k];
    } else {
        int o2 = o - IN_DIM * HID;
        if (o2 < HID * OUT_DIM) {
            int k = o2 / OUT_DIM, oo = o2 % OUT_DIM;   // fcT[k][o] = fc_w[o][k]
            fcT[o2] = fc_w[oo * HID + k];
        }
    }
}

// ============================================================
// K3-fused SELF-CONTAINED: 256 blocks, one batch row each, ZERO
//  inter-block communication (deadlock impossible, dispatch-order
//  independent). Per block b:
//   phase 1: xd[:,b,:] ingemm (64-row t-tiles, k-tile 32, acc[32])
//   phase 2: scan (R11 verbatim — bit-identical numerics)
//   phase 3: out[:,b,:] outgemm (512-row t-tiles, k-tile 32)
//  fp order of every element identical to the validated R11
//  pipeline (k/h ascending, same tiling) -> bit-identical output.
//  (512,2): VGPR cap 128 (empirical: R11 scan=108 fits; R12's
//  (512,4) capped at 64 and spilled). Phases have disjoint
//  pressure; tables loaded after phase 1.
// ============================================================

#define PAIR2(base, ii)                                              \
    {                                                                \
        unsigned int pk = idp[ii];                                   \
        float g0 = *(const float*)((base) + (pk & 0xffffu));         \
        float g1 = *(const float*)((base) + (pk >> 16));             \
        a0 = fmaf(val[2*(ii)],     g0, a0);                          \
        a1 = fmaf(val[2*(ii) + 1], g1, a1);                          \
    }

#define CHUNK2(base, c)                                              \
    PAIR2(base, 2*(c)+0) PAIR2(base, 2*(c)+1)

__device__ __forceinline__ float sparse_accum(
    const char* base, const float (&val)[MAXNNZ],
    const unsigned int (&idp)[MAXNNZ / 2], int nch, float a_init)
{
    float a0 = a_init, a1 = 0.f;
    switch (nch) {
        case 24: CHUNK2(base, 23) [[fallthrough]];
        case 23: CHUNK2(base, 22) [[fallthrough]];
        case 22: CHUNK2(base, 21) [[fallthrough]];
        case 21: CHUNK2(base, 20) [[fallthrough]];
        case 20: CHUNK2(base, 19) [[fallthrough]];
        case 19: CHUNK2(base, 18) [[fallthrough]];
        case 18: CHUNK2(base, 17) [[fallthrough]];
        case 17: CHUNK2(base, 16) [[fallthrough]];
        case 16: CHUNK2(base, 15) [[fallthrough]];
        case 15: CHUNK2(base, 14) [[fallthrough]];
        case 14: CHUNK2(base, 13) [[fallthrough]];
        case 13: CHUNK2(base, 12) [[fallthrough]];
        case 12: CHUNK2(base, 11) [[fallthrough]];
        case 11: CHUNK2(base, 10) [[fallthrough]];
        case 10: CHUNK2(base,  9) [[fallthrough]];
        case  9: CHUNK2(base,  8) [[fallthrough]];
        case  8: CHUNK2(base,  7) [[fallthrough]];
        case  7: CHUNK2(base,  6) [[fallthrough]];
        case  6: CHUNK2(base,  5) [[fallthrough]];
        case  5: CHUNK2(base,  4) [[fallthrough]];
        case  4: CHUNK2(base,  3) [[fallthrough]];
        case  3: CHUNK2(base,  2) [[fallthrough]];
        case  2: CHUNK2(base,  1) [[fallthrough]];
        case  1: CHUNK2(base,  0) break;
        default: break;
    }
    return a0 + a1;
}

__global__ __launch_bounds__(512, 2) void fused_kernel(
    const float* __restrict__ x, const float* __restrict__ w_inT,
    const float* __restrict__ b_in, const float* __restrict__ b_h,
    float* __restrict__ act_g,
    const float* __restrict__ val_t, const unsigned short* __restrict__ idx_t,
    const unsigned int* __restrict__ perm, const unsigned int* __restrict__ nnzR,
    const float* __restrict__ fcT, const float* __restrict__ fc_b,
    float* __restrict__ out_g)
{
    __shared__ float smem[1024 + 512 * 33];   // sbuf | xl(64x33)/al(512x33)
    int tid = threadIdx.x;
    int b   = blockIdx.x;

    // ---------- phase 1: ingemm xd[:,b,:] ----------
    {
        float* xl = smem + 1024;              // [64][33]
        int r = tid & 63;                     // t-row within tile
        int g = tid >> 6;                     // wave id -> col group
        for (int mt = 0; mt < 16; mt++) {     // 16 x 64 = 1024 >= 1000
            int t0 = mt * 64;
            for (int nc = 0; nc < 2; nc++) {
                int n0 = nc * 256 + g * 32;
                float acc[32];
#pragma unroll
                for (int j = 0; j < 32; j++) acc[j] = b_in[n0 + j] + b_h[n0 + j];
                for (int k0 = 0; k0 < IN_DIM; k0 += 32) {
                    __syncthreads();
                    {
                        int rr = tid >> 3, cc = tid & 7;   // 512 float4 = 64x32
                        if (t0 + rr < T_STEPS) {
                            float4 v = *(const float4*)(
                                x + ((t0 + rr) * BATCH + b) * IN_DIM + k0 + cc * 4);
                            float* d = &xl[rr * 33 + cc * 4];
                            d[0] = v.x; d[1] = v.y; d[2] = v.z; d[3] = v.w;
                        }
                    }
                    __syncthreads();
                    if (t0 + r < T_STEPS) {
                        const float* xrow = &xl[r * 33];
#pragma unroll
                        for (int kk = 0; kk < 32; kk++) {
                            float a = xrow[kk];
                            const float* wrow = w_inT + (k0 + kk) * HID + n0; // uniform
#pragma unroll
                            for (int j = 0; j < 32; j++)
                                acc[j] = fmaf(a, wrow[j], acc[j]);
                        }
                    }
                }
                if (t0 + r < T_STEPS) {
                    float* orow = act_g + ((t0 + r) * BATCH + b) * HID + n0;
#pragma unroll
                    for (int j = 0; j < 8; j++)
                        *(float4*)(orow + j * 4) =
                            make_float4(acc[4*j], acc[4*j+1], acc[4*j+2], acc[4*j+3]);
                }
            }
        }
    }
    __syncthreads();
    __threadfence();                          // xd stores -> scan loads (L1 safety)

    // ---------- phase 2: scan (R11 verbatim) ----------
    {
        float* sbuf = smem;                   // [1024]
        sbuf[tid] = 0.f;

        float        val[MAXNNZ];
        unsigned int idp[MAXNNZ / 2];
        {
            const float4* vp = (const float4*)(val_t + tid * MAXNNZ);
#pragma unroll
            for (int i = 0; i < MAXNNZ / 4; i++) {
                float4 v = vp[i];
                val[4*i] = v.x; val[4*i+1] = v.y; val[4*i+2] = v.z; val[4*i+3] = v.w;
            }
            const uint4* ip = (const uint4*)(idx_t + tid * MAXNNZ);
#pragma unroll
            for (int i = 0; i < MAXNNZ / 8; i++) {
                uint4 u = ip[i];
                idp[4*i] = u.x; idp[4*i+1] = u.y; idp[4*i+2] = u.z; idp[4*i+3] = u.w;
            }
        }
        int h = (int)perm[tid];
        int wmax = (int)nnzR[tid | 63];       // sched S, wave-uniform
        wmax = __builtin_amdgcn_readfirstlane(wmax);
        int nch = (wmax + 3) >> 2;            // chunks of 4 slots (2 pairs)

        float state = 0.f;
        int gi = b * HID + h;
        float xdv = act_g[gi];                // xd[0]
        const char* sb = (const char*)sbuf;
        __syncthreads();

        for (int t = 0; t < T_STEPS; t += 2) {
            { // even step: read region0, write region1
                float xn = act_g[gi + BATCH * HID];
                float a = sparse_accum(sb, val, idp, nch, xdv);
                state = state * OMA_F + a * ALPHA_F;
                float act = fmaxf(state, 0.f);
                sbuf[512 + h] = act;
                __syncthreads();
                act_g[gi] = act;              // store after barrier
                gi += BATCH * HID;
                xdv = xn;
            }
            { // odd step: read region1, write region0
                int gn = (t < T_STEPS - 2) ? gi + BATCH * HID : gi;
                float xn = act_g[gn];
                float a = sparse_accum(sb + 2048, val, idp, nch, xdv);
                state = state * OMA_F + a * ALPHA_F;
                float act = fmaxf(state, 0.f);
                sbuf[h] = act;
                __syncthreads();
                act_g[gi] = act;              // store after barrier
                gi += BATCH * HID;
                xdv = xn;
            }
        }
    }
    __syncthreads();
    __threadfence();                          // act stores -> outgemm loads

    // ---------- phase 3: outgemm out[:,b,:] ----------
    {
        float* al = smem + 1024;              // [512][33]
        for (int mt2 = 0; mt2 < 2; mt2++) {
            int t0 = mt2 * 512;
            int t  = t0 + tid;
            float acc[32];
#pragma unroll
            for (int o = 0; o < 32; o++) acc[o] = fc_b[o];
            for (int k0 = 0; k0 < HID; k0 += 32) {
                __syncthreads();
#pragma unroll
                for (int i = 0; i < 8; i++) {
                    int f = tid + i * 512, rr = f >> 3, cc = f & 7;
                    if (t0 + rr < T_STEPS) {
                        float4 v = *(const float4*)(
                            act_g + ((t0 + rr) * BATCH + b) * HID + k0 + cc * 4);
                        float* d = &al[rr * 33 + cc * 4];
                        d[0] = v.x; d[1] = v.y; d[2] = v.z; d[3] = v.w;
                    }
                }
                __syncthreads();
                if (t < T_STEPS) {
                    const float* arow = &al[tid * 33];
#pragma unroll
                    for (int kk = 0; kk < 32; kk++) {
                        float a = arow[kk];
                        const float* frow = fcT + (k0 + kk) * OUT_DIM;  // uniform
#pragma unroll
                        for (int o = 0; o < 32; o++)
                            acc[o] = fmaf(a, frow[o], acc[o]);
                    }
                }
            }
            if (t < T_STEPS) {
                float* orow = out_g + (t * BATCH + b) * OUT_DIM;
#pragma unroll
                for (int j = 0; j < 8; j++)
                    *(float4*)(orow + j * 4) =
                        make_float4(acc[4*j], acc[4*j+1], acc[4*j+2], acc[4*j+3]);
            }
        }
    }
}

// ============================================================
extern "C" void kernel_launch(void* const* d_in, const int* in_sizes, int n_in,
                              void* d_out, int out_size, void* d_ws, size_t ws_size,
                              hipStream_t stream)
{
    const float* x      = (const float*)d_in[0];
    const float* w_in   = (const float*)d_in[1];
    const float* b_in   = (const float*)d_in[2];
    const float* w_h    = (const float*)d_in[3];
    const float* b_h    = (const float*)d_in[4];
    const float* dale   = (const float*)d_in[5];
    const float* sparse = (const float*)d_in[6];
    const float* fc_w   = (const float*)d_in[7];
    const float* fc_b   = (const float*)d_in[8];

    float* out_g = (float*)d_out;
    float* act_g = out_g + (long)T_STEPS * BATCH * OUT_DIM;  // rnn_activity slab

    char* ws = (char*)d_ws;
    float*          val_t = (float*)(ws + 0);
    unsigned short* idx_t = (unsigned short*)(ws + 196608);
    unsigned int*   perm  = (unsigned int*)(ws + 294912);
    unsigned int*   nnzR  = (unsigned int*)(ws + 296960);
    float*          w_inT = (float*)(ws + 299008);
    float*          fcT   = (float*)(ws + 561152);

    build_rank_kernel<<<1, 512, 0, stream>>>(w_h, sparse, perm, nnzR);
    fill_kernel<<<HID, 64, 0, stream>>>(w_h, dale, sparse, perm, nnzR, val_t, idx_t);
    sched_kernel<<<8, 64, 0, stream>>>(val_t, idx_t, nnzR);
    trans_kernel<<<320, 256, 0, stream>>>(w_in, fc_w, w_inT, fcT);
    fused_kernel<<<BATCH, 512, 0, stream>>>(x, w_inT, b_in, b_h, act_g,
                                            val_t, idx_t, perm, nnzR,
                                            fcT, fc_b, out_g);
}

// Round 15
// 2062.783 us; speedup vs baseline: 40.6668x; 1.8959x over previous
//
#include <hip/hip_runtime.h>

#define T_STEPS 1000
#define BATCH   256
#define IN_DIM  128
#define HID     512
#define OUT_DIM 32
#define ALPHA_F 0.2f
#define OMA_F   0.8f
#define MAXNNZ  96   // Binomial(511,0.1) max over 512 rows ~ 75; 96 is 6.5 sigma
#define BDEPTH  20   // per-(lane,bank) bucket depth; P(overflow) ~ 0
#define HSLOT   48   // per-half slot capacity (S<=96 -> each half <=48)

// ---- workspace layout (byte offsets, all 16B aligned) ----
// val_t : float  [HID][MAXNNZ]                          @ 0        (196608 B)
// idx_t : ushort [HID][MAXNNZ]                          @ 196608   (98304 B)
// perm  : uint   [HID]                                  @ 294912   (2048 B)
// nnzR  : uint   [HID]  nnz -> sched S                  @ 296960   (2048 B)
// w_inT : float  [IN_DIM][HID]                          @ 299008   (262144 B)
// fcT   : float  [HID][OUT_DIM]                         @ 561152   (65536 B)

// ============================================================
// K2a: counts + deterministic rank (stable sort by (c, h)).
// ============================================================
__global__ __launch_bounds__(512) void build_rank_kernel(
    const float* __restrict__ w_h, const float* __restrict__ sparse,
    unsigned int* __restrict__ perm, unsigned int* __restrict__ nnzR)
{
    int tid = threadIdx.x;           // row h
    __shared__ int cnt_sh[HID];

    const float4* wr4 = (const float4*)(w_h    + tid * HID);
    const float4* sr4 = (const float4*)(sparse + tid * HID);
    int cnt = 0;
    for (int j4 = 0; j4 < HID / 4; j4++) {
        float4 w = wr4[j4];
        float4 s = sr4[j4];
        if (w.x > 0.f && s.x > 0.5f) cnt++;
        if (w.y > 0.f && s.y > 0.5f) cnt++;
        if (w.z > 0.f && s.z > 0.5f) cnt++;
        if (w.w > 0.f && s.w > 0.5f) cnt++;
    }
    int c = min(cnt, MAXNNZ);

    cnt_sh[tid] = c;
    __syncthreads();
    int rank = 0;
    for (int j = 0; j < HID; j++) {
        int cj = cnt_sh[j];                     // broadcast read
        rank += (cj < c) || (cj == c && j < tid);
    }
    perm[rank] = (unsigned int)tid;
    nnzR[rank] = (unsigned int)c;
}

// ============================================================
// K2b: wave-parallel fill, one rank per block (1 wave).
// ============================================================
__global__ __launch_bounds__(64) void fill_kernel(
    const float* __restrict__ w_h, const float* __restrict__ dale,
    const float* __restrict__ sparse,
    const unsigned int* __restrict__ perm, const unsigned int* __restrict__ nnzR,
    float* __restrict__ val_t, unsigned short* __restrict__ idx_t)
{
    int r    = blockIdx.x;           // rank
    int lane = threadIdx.x;          // 0..63
    int h = (int)perm[r];
    int c = (int)nnzR[r];

    float*          vout = val_t + r * MAXNNZ;
    unsigned short* iout = idx_t + r * MAXNNZ;

    for (int k = lane; k < MAXNNZ; k += 64)
        if (k >= c) { vout[k] = 0.f; iout[k] = 0; }

    unsigned long long lt = (1ull << lane) - 1ull;
    int pos_base = 0;
#pragma unroll
    for (int ch = 0; ch < 8; ch++) {
        int j = ch * 64 + lane;
        float w = w_h[h * HID + j];
        float s = sparse[h * HID + j];
        bool pred = (w > 0.f) && (s > 0.5f);
        unsigned long long m = __ballot(pred);
        if (pred) {
            int pos = pos_base + (int)__popcll(m & lt);
            if (pos < MAXNNZ) {
                vout[pos] = w * dale[j];
                iout[pos] = (unsigned short)(j * 4);   // LDS byte offset
            }
        }
        pos_base += (int)__popcll(m);
    }
}

// ============================================================
// K2d: capped gather scheduler (R11 — proven deterministic,
//      conflicts 3.43e8 -> 2.05e8).
// ============================================================
__global__ __launch_bounds__(64) void sched_kernel(
    float* __restrict__ val_t, unsigned short* __restrict__ idx_t,
    unsigned int* __restrict__ nnzR)
{
    int w    = blockIdx.x;           // scan-wave id 0..7
    int lane = threadIdx.x;          // 0..63
    int rank = w * 64 + lane;
    int g    = lane >> 5;            // phase-group 0/1
    int l32  = lane & 31;

    __shared__ unsigned short entb[64][32][BDEPTH]; // (src<<9)|word
    __shared__ unsigned char  cntb[64][32];
    __shared__ unsigned char  outsrc[64][MAXNNZ];
    __shared__ float          vll[64][MAXNNZ];
    __shared__ volatile int   wbuf[2][32];

    int c = (int)nnzR[rank];
    int S = c;
#pragma unroll
    for (int off = 32; off; off >>= 1) S = max(S, __shfl_xor(S, off));

    for (int b = 0; b < 32; b++) cntb[lane][b] = 0;
    for (int e = 0; e < MAXNNZ; e++) {
        vll[lane][e]    = val_t[rank * MAXNNZ + e];
        outsrc[lane][e] = 255;
    }
    unsigned int bm = 0;
    int rem = 0;
    for (int e = 0; e < c; e++) {
        int word = ((int)idx_t[rank * MAXNNZ + e]) >> 2;  // 0..511
        int b = word & 31;
        int k = (int)cntb[lane][b];
        if (k < BDEPTH) {
            entb[lane][b][k] = (unsigned short)((e << 9) | word);
            cntb[lane][b] = (unsigned char)(k + 1);
            bm |= 1u << b;
            rem++;
        }
    }

    for (int s = 0; s < MAXNNZ; s++) {
        if (s < S) {
            unsigned int claimed = 0;
            int myb = -1;
#pragma unroll
            for (int round = 0; round < 2; round++) {
                int prop = -1;
                if (myb < 0 && rem > 0) {
                    unsigned int avail = bm & ~claimed;
                    if (avail) {
                        int rot = (l32 * 7 + s * 3 + round * 11) & 31;
                        unsigned int av2 = (avail >> rot) | (avail << ((32 - rot) & 31));
                        prop = (__ffs(av2) - 1 + rot) & 31;
                    }
                }
                if (prop >= 0) wbuf[g][prop] = lane;        // race: HW lane priority
                int won = 0;
                if (prop >= 0 && wbuf[g][prop] == lane) { myb = prop; won = 1; }
                unsigned int cm = won ? (1u << myb) : 0u;
#pragma unroll
                for (int off = 16; off; off >>= 1)
                    cm |= (unsigned int)__shfl_xor((int)cm, off, 32);
                claimed |= cm;
            }
            if (myb < 0 && rem > 0 && rem >= S - s) {       // forced (rare)
                unsigned int a = bm & ~claimed;
                myb = a ? (__ffs(a) - 1) : (__ffs(bm) - 1);
            }
            if (myb >= 0) {
                int k = (int)cntb[lane][myb] - 1;
                unsigned short pk = entb[lane][myb][k];
                cntb[lane][myb] = (unsigned char)k;
                if (k == 0) bm &= ~(1u << myb);
                outsrc[lane][s] = (unsigned char)(pk >> 9);
                idx_t[rank * MAXNNZ + s] = (unsigned short)((pk & 511) * 4);
                rem--;
            } else {
                unsigned int freeb = ~claimed;
                int pb = freeb ? (__ffs(freeb) - 1) : 0;
                idx_t[rank * MAXNNZ + s] = (unsigned short)(pb * 4);
            }
        } else {
            idx_t[rank * MAXNNZ + s] = 0;
        }
    }
    nnzR[rank] = (unsigned int)S;

    for (int s = 0; s < MAXNNZ; s++) {
        int src = outsrc[lane][s];
        val_t[rank * MAXNNZ + s] = (src == 255) ? 0.f : vll[lane][src];
    }
}

// ============================================================
// K2c: weight transposes, grid-parallel.
// ============================================================
__global__ __launch_bounds__(256) void trans_kernel(
    const float* __restrict__ w_in, const float* __restrict__ fc_w,
    float* __restrict__ w_inT, float* __restrict__ fcT)
{
    int o = blockIdx.x * 256 + threadIdx.x;
    if (o < IN_DIM * HID) {
        int k = o / HID, n = o % HID;          // w_inT[k][n] = w_in[n][k]
        w_inT[o] = w_in[n * IN_DIM + k];
    } else {
        int o2 = o - IN_DIM * HID;
        if (o2 < HID * OUT_DIM) {
            int k = o2 / OUT_DIM, oo = o2 % OUT_DIM;   // fcT[k][o] = fc_w[o][k]
            fcT[o2] = fc_w[oo * HID + k];
        }
    }
}

// ============================================================
// K1: xd[m][h] = x[m]@w_in^T + b_in + b_h  into activity slab.
//     Grid 16000 = 1000 m-tiles x 16 n-chunks (XCD-swizzled).
//     k-tile 32 in LDS (33 KB -> 4 blocks/CU, 16 waves/CU).
// ============================================================
__global__ __launch_bounds__(256, 4) void ingemm_kernel(
    const float* __restrict__ x, const float* __restrict__ w_inT,
    const float* __restrict__ b_in, const float* __restrict__ b_h,
    float* __restrict__ xd)
{
    __shared__ float xl[256 * 33];   // [row][33] pad -> (tid+kk)%32 banks, 2-way
    int tid = threadIdx.x;
    // de-swizzle: B = r8 + 8*(nc + 16*a); mb = 8a + r8 -> B%8 == mb%8
    int B  = blockIdx.x;
    int r8 = B & 7;
    int tt = B >> 3;
    int nc = tt & 15;
    int aa = tt >> 4;
    int mb = 8 * aa + r8;            // 0..999
    long m0 = (long)mb * 256;
    int n0 = nc * 32;

    float acc[32];
#pragma unroll
    for (int j = 0; j < 32; j++) acc[j] = b_in[n0 + j] + b_h[n0 + j];

    for (int k0 = 0; k0 < IN_DIM; k0 += 32) {
        __syncthreads();
#pragma unroll
        for (int i = 0; i < 8; i++) {
            int f  = tid + i * 256;      // 0..2047 float4s
            int rr = f >> 3, cc = f & 7;
            float4 v = *(const float4*)(x + (m0 + rr) * IN_DIM + k0 + cc * 4);
            float* d = &xl[rr * 33 + cc * 4];   // 132B rows: scalar writes (align)
            d[0] = v.x; d[1] = v.y; d[2] = v.z; d[3] = v.w;
        }
        __syncthreads();
        const float* xrow = &xl[tid * 33];
#pragma unroll
        for (int kk = 0; kk < 32; kk++) {
            float a = xrow[kk];
            const float* wrow = w_inT + (k0 + kk) * HID + n0;  // uniform -> s_load
#pragma unroll
            for (int j = 0; j < 32; j++) acc[j] = fmaf(a, wrow[j], acc[j]);
        }
    }
    float* orow = xd + (m0 + tid) * HID + n0;
#pragma unroll
    for (int j = 0; j < 8; j++)
        *(float4*)(orow + j * 4) =
            make_float4(acc[4*j], acc[4*j+1], acc[4*j+2], acc[4*j+3]);
}

// ============================================================
// K3: SPLIT-GATHER scan. 256 blocks x 1024 threads (16 waves/CU,
//     2x the TLP of the 512-thread version). Thread r (half A)
//     takes chunks [0,nchA) + xd + state; thread 512+r (half B)
//     takes chunks [nchA,nchT), deposits partial in pbuf[r].
//     Per-thread table halves to 48 slots (~75 VGPR; block=1024
//     caps allocator at 128 -> no spill). Deterministic: fixed
//     A+B split, fixed order within each half.
// ============================================================

#define PAIR2(base, ii)                                              \
    {                                                                \
        unsigned int pk = idp[ii];                                   \
        float g0 = *(const float*)((base) + (pk & 0xffffu));         \
        float g1 = *(const float*)((base) + (pk >> 16));             \
        a0 = fmaf(val[2*(ii)],     g0, a0);                          \
        a1 = fmaf(val[2*(ii) + 1], g1, a1);                          \
    }

#define CHUNK2(base, c)                                              \
    PAIR2(base, 2*(c)+0) PAIR2(base, 2*(c)+1)

__device__ __forceinline__ float sparse_accum(
    const char* base, const float (&val)[HSLOT],
    const unsigned int (&idp)[HSLOT / 2], int nch, float a_init)
{
    float a0 = a_init, a1 = 0.f;
    switch (nch) {
        case 12: CHUNK2(base, 11) [[fallthrough]];
        case 11: CHUNK2(base, 10) [[fallthrough]];
        case 10: CHUNK2(base,  9) [[fallthrough]];
        case  9: CHUNK2(base,  8) [[fallthrough]];
        case  8: CHUNK2(base,  7) [[fallthrough]];
        case  7: CHUNK2(base,  6) [[fallthrough]];
        case  6: CHUNK2(base,  5) [[fallthrough]];
        case  5: CHUNK2(base,  4) [[fallthrough]];
        case  4: CHUNK2(base,  3) [[fallthrough]];
        case  3: CHUNK2(base,  2) [[fallthrough]];
        case  2: CHUNK2(base,  1) [[fallthrough]];
        case  1: CHUNK2(base,  0) break;
        default: break;
    }
    return a0 + a1;
}

__global__ __launch_bounds__(1024) void scan_kernel(
    float* __restrict__ act_g,
    const float* __restrict__ val_t, const unsigned short* __restrict__ idx_t,
    const unsigned int* __restrict__ perm, const unsigned int* __restrict__ nnzR)
{
    int tid = threadIdx.x;
    int r   = tid & 511;              // rank
    int isB = tid >> 9;               // 0 = half A, 1 = half B
    int b   = blockIdx.x;
    __shared__ float sbuf[1024];      // [0..511] region0, [512..1023] region1
    __shared__ float pbuf[512];       // B-half partials
    sbuf[tid & 1023] = 0.f;           // tid covers both regions (1024 threads)

    int S = (int)nnzR[r | 63];        // sched S, wave-uniform (r|63 const/wave)
    S = __builtin_amdgcn_readfirstlane(S);
    int nchT = (S + 3) >> 2;          // total chunks of 4 slots
    int nchA = (nchT + 1) >> 1;
    int nch  = isB ? (nchT - nchA) : nchA;
    int base = isB ? (nchA << 2) : 0; // slot offset (mult of 4 -> aligned loads)

    // load this thread's HALF of the table (static indexing only)
    float        val[HSLOT];
    unsigned int idp[HSLOT / 2];
    {
        const float4* vp = (const float4*)(val_t + r * MAXNNZ + base);
#pragma unroll
        for (int i = 0; i < HSLOT / 4; i++) {
            float4 v = vp[i];
            val[4*i] = v.x; val[4*i+1] = v.y; val[4*i+2] = v.z; val[4*i+3] = v.w;
        }
        const uint2* ip = (const uint2*)(idx_t + r * MAXNNZ + base); // 8B aligned
#pragma unroll
        for (int i = 0; i < HSLOT / 4; i++) {   // 48 u16 = 12 uint2
            uint2 u = ip[i];
            idp[2*i] = u.x; idp[2*i+1] = u.y;
        }
    }
    int h = (int)perm[r];

    float state = 0.f;
    int gi = b * HID + h;
    float xdv = 0.f;
    if (!isB) xdv = act_g[gi];        // xd[0] (A only)
    const char* sb = (const char*)sbuf;
    __syncthreads();

    for (int t = 0; t < T_STEPS; t += 2) {
        { // even step: read region0, write region1
            float xn = 0.f;
            if (!isB) xn = act_g[gi + BATCH * HID];
            float ap = sparse_accum(sb, val, idp, nch, isB ? 0.f : xdv);
            if (isB) pbuf[r] = ap;
            __syncthreads();          // pbuf ready; region0 reads done
            float act = 0.f;
            if (!isB) {
                float a = ap + pbuf[r];
                state = state * OMA_F + a * ALPHA_F;
                act = fmaxf(state, 0.f);
                sbuf[512 + h] = act;
            }
            __syncthreads();          // region1 ready
            if (!isB) act_g[gi] = act;
            gi += BATCH * HID;
            xdv = xn;
        }
        { // odd step: read region1 (+2048B), write region0
            float xn = 0.f;
            if (!isB) {
                int gn = (t < T_STEPS - 2) ? gi + BATCH * HID : gi;
                xn = act_g[gn];
            }
            float ap = sparse_accum(sb + 2048, val, idp, nch, isB ? 0.f : xdv);
            if (isB) pbuf[r] = ap;
            __syncthreads();
            float act = 0.f;
            if (!isB) {
                float a = ap + pbuf[r];
                state = state * OMA_F + a * ALPHA_F;
                act = fmaxf(state, 0.f);
                sbuf[h] = act;
            }
            __syncthreads();
            if (!isB) act_g[gi] = act;
            gi += BATCH * HID;
            xdv = xn;
        }
    }
}

// ============================================================
// K4: out[m][o] = act[m]@fc_w^T + fc_b. k-tile 32 in LDS
//     (33 KB -> 4 blocks/CU), uniform s_load weights.
// ============================================================
__global__ __launch_bounds__(256, 4) void outgemm_kernel(
    const float* __restrict__ act_g, const float* __restrict__ fcT,
    const float* __restrict__ fc_b, float* __restrict__ out_g)
{
    __shared__ float al[256 * 33];
    int tid = threadIdx.x;
    long m0 = (long)blockIdx.x * 256;

    float acc[32];
#pragma unroll
    for (int o = 0; o < 32; o++) acc[o] = fc_b[o];

    for (int k0 = 0; k0 < HID; k0 += 32) {
        __syncthreads();
#pragma unroll
        for (int i = 0; i < 8; i++) {
            int f  = tid + i * 256;      // 0..2047 float4s
            int rr = f >> 3, cc = f & 7;
            float4 v = *(const float4*)(act_g + (m0 + rr) * HID + k0 + cc * 4);
            float* d = &al[rr * 33 + cc * 4];
            d[0] = v.x; d[1] = v.y; d[2] = v.z; d[3] = v.w;
        }
        __syncthreads();
        const float* arow = &al[tid * 33];
#pragma unroll
        for (int kk = 0; kk < 32; kk++) {
            float a = arow[kk];
            const float* frow = fcT + (k0 + kk) * OUT_DIM;  // uniform -> s_load
#pragma unroll
            for (int o = 0; o < 32; o++) acc[o] = fmaf(a, frow[o], acc[o]);
        }
    }
    float* orow = out_g + (m0 + tid) * OUT_DIM;
#pragma unroll
    for (int j = 0; j < 8; j++)
        *(float4*)(orow + j * 4) =
            make_float4(acc[4*j], acc[4*j+1], acc[4*j+2], acc[4*j+3]);
}

// ============================================================
extern "C" void kernel_launch(void* const* d_in, const int* in_sizes, int n_in,
                              void* d_out, int out_size, void* d_ws, size_t ws_size,
                              hipStream_t stream)
{
    const float* x      = (const float*)d_in[0];
    const float* w_in   = (const float*)d_in[1];
    const float* b_in   = (const float*)d_in[2];
    const float* w_h    = (const float*)d_in[3];
    const float* b_h    = (const float*)d_in[4];
    const float* dale   = (const float*)d_in[5];
    const float* sparse = (const float*)d_in[6];
    const float* fc_w   = (const float*)d_in[7];
    const float* fc_b   = (const float*)d_in[8];

    float* out_g = (float*)d_out;
    float* act_g = out_g + (long)T_STEPS * BATCH * OUT_DIM;  // rnn_activity slab

    char* ws = (char*)d_ws;
    float*          val_t = (float*)(ws + 0);
    unsigned short* idx_t = (unsigned short*)(ws + 196608);
    unsigned int*   perm  = (unsigned int*)(ws + 294912);
    unsigned int*   nnzR  = (unsigned int*)(ws + 296960);
    float*          w_inT = (float*)(ws + 299008);
    float*          fcT   = (float*)(ws + 561152);

    build_rank_kernel<<<1, 512, 0, stream>>>(w_h, sparse, perm, nnzR);
    fill_kernel<<<HID, 64, 0, stream>>>(w_h, dale, sparse, perm, nnzR, val_t, idx_t);
    sched_kernel<<<8, 64, 0, stream>>>(val_t, idx_t, nnzR);
    trans_kernel<<<320, 256, 0, stream>>>(w_in, fc_w, w_inT, fcT);
    ingemm_kernel<<<16000, 256, 0, stream>>>(x, w_inT, b_in, b_h, act_g);
    scan_kernel<<<256, 1024, 0, stream>>>(act_g, val_t, idx_t, perm, nnzR);
    outgemm_kernel<<<1000, 256, 0, stream>>>(act_g, fcT, fc_b, out_g);
}